// Round 5
// baseline (172.617 us; speedup 1.0000x reference)
//
#include <hip/hip_runtime.h>
#include <hip/hip_bf16.h>

// ConvolutionalSelfAttention — algebraically reduced:
//   Kn[b,n,:] = normalize(x[b,n,:] @ key_w^T + key_b)      (bf16, via MFMA)
//   Qn[b,m,:] = normalize(x[b,m,:] @ query_w^T + query_b)  (bf16, via MFMA)
//   v[b,n]    = x[b,n,:] @ value_w^T + value_b             (fp32)
//   S[b,n,m]  = Kn[b,n]·Qn[b,m]   (|S|<=1, exp stable without max-sub)
//   R[b,m]    = (sum_n v e^S) / (sum_n e^S)                (fused, S never stored)
//   out[b,c,i,j] = 3x3 box sum of R[b,m]*x[b,c,m]  (x in bf16 copy xc)
// local_indices unused (windows are complete 3x3, order-invariant).
// R4->R5: attn m-tile 32->64 (halves redundant Kn L2 reads, 256 blocks x 8
//         waves each owning an n-eighth); wconv folded into fused_lin via
//         inline fp32->bf16 weight conversion (one fewer launch).
// ws: xc 8MB | Kn 8MB | Qn 8MB | v 64KB | R 64KB

#define NB 16
#define NC 256
#define NHW 1024
#define NCH 30

typedef __attribute__((ext_vector_type(8))) short short8;
typedef __attribute__((ext_vector_type(4))) float f32x4;

static __device__ __forceinline__ unsigned short f2bf(float f) {
    __hip_bfloat16 h = __float2bfloat16(f);
    return *(unsigned short*)&h;
}
static __device__ __forceinline__ float bf2f(unsigned short u) {
    unsigned int x = ((unsigned int)u) << 16;
    return __uint_as_float(x);
}
static __device__ __forceinline__ short8 ldw_bf16(const float* p) {
    // load 8 consecutive fp32 and round to a bf16 A/B fragment
    float4 a = *(const float4*)(p);
    float4 b = *(const float4*)(p + 4);
    short8 r;
    r[0] = (short)f2bf(a.x); r[1] = (short)f2bf(a.y);
    r[2] = (short)f2bf(a.z); r[3] = (short)f2bf(a.w);
    r[4] = (short)f2bf(b.x); r[5] = (short)f2bf(b.y);
    r[6] = (short)f2bf(b.z); r[7] = (short)f2bf(b.w);
    return r;
}

// Fused: transpose batch -> (LDS fp32 slab, xc bf16 copy) + v + MFMA linears
// (weights converted fp32->bf16 inline) + row-normalize -> Kn, Qn.
// Grid (16 n-tiles, B), 512 threads (8 waves: nw = wave&3 picks 16-row
// n-subtile, ch = wave>>2 picks 128-col co-half).
__global__ __launch_bounds__(512) void fused_lin_kernel(
    const float* __restrict__ batch,
    const float* __restrict__ value_w, const float* __restrict__ value_b,
    const float* __restrict__ key_w, const float* __restrict__ query_w,
    const float* __restrict__ key_b, const float* __restrict__ query_b,
    unsigned short* __restrict__ xc,
    unsigned short* __restrict__ Kn, unsigned short* __restrict__ Qn,
    float* __restrict__ vout)
{
    const int b = blockIdx.y, n0 = blockIdx.x * 64;
    const int t = threadIdx.x, wave = t >> 6, lane = t & 63;
    const int nw = wave & 3, ch = wave >> 2;
    const int l15 = lane & 15, quad = lane >> 4;

    __shared__ float Xs[2][64][65];          // [buf][k-in-slab][n], stride 65
    __shared__ float PK[2][4][16], PQ[2][4][16];
    __shared__ float4 vred[8][16];

    // staging roles: thread loads rows c_l and c_l+32 of the 64-c slab, 4 n's
    const int c_l = t >> 4;                  // 0..31  (= wave*4 + quad)
    const int n4  = (t & 15) * 4;
    const float* bb = batch + (size_t)b * NC * NHW + n0;
    unsigned short* xcp = xc + (size_t)b * NC * NHW + n0;
    float4 vacc = {0.f, 0.f, 0.f, 0.f};

    float4 x0, x1;
    // prologue: load slab 0
    {
        int c0 = c_l, c1 = c_l + 32;
        x0 = *(const float4*)(bb + (size_t)c0 * NHW + n4);
        x1 = *(const float4*)(bb + (size_t)c1 * NHW + n4);
        ushort4 o0, o1;
        o0.x = f2bf(x0.x); o0.y = f2bf(x0.y); o0.z = f2bf(x0.z); o0.w = f2bf(x0.w);
        o1.x = f2bf(x1.x); o1.y = f2bf(x1.y); o1.z = f2bf(x1.z); o1.w = f2bf(x1.w);
        *(ushort4*)(xcp + (size_t)c0 * NHW + n4) = o0;
        *(ushort4*)(xcp + (size_t)c1 * NHW + n4) = o1;
        float w0 = value_w[c0], w1 = value_w[c1];
        vacc.x += x0.x * w0 + x1.x * w1; vacc.y += x0.y * w0 + x1.y * w1;
        vacc.z += x0.z * w0 + x1.z * w1; vacc.w += x0.w * w0 + x1.w * w1;
        float* r0 = &Xs[0][c_l][n4];
        r0[0] = x0.x; r0[1] = x0.y; r0[2] = x0.z; r0[3] = x0.w;
        float* r1 = &Xs[0][c_l + 32][n4];
        r1[0] = x1.x; r1[1] = x1.y; r1[2] = x1.z; r1[3] = x1.w;
    }
    __syncthreads();

    f32x4 accK[8], accQ[8];
    #pragma unroll
    for (int ct = 0; ct < 8; ++ct) {
        int co = ch * 128 + ct * 16 + l15;
        float bK = key_b[co], bQ = query_b[co];
        accK[ct] = (f32x4){bK, bK, bK, bK};
        accQ[ct] = (f32x4){bQ, bQ, bQ, bQ};
    }

    for (int cc = 0; cc < 4; ++cc) {
        // prefetch next slab into registers (latency hidden by MFMA below)
        if (cc < 3) {
            int c0 = (cc + 1) * 64 + c_l, c1 = c0 + 32;
            x0 = *(const float4*)(bb + (size_t)c0 * NHW + n4);
            x1 = *(const float4*)(bb + (size_t)c1 * NHW + n4);
            ushort4 o0, o1;
            o0.x = f2bf(x0.x); o0.y = f2bf(x0.y); o0.z = f2bf(x0.z); o0.w = f2bf(x0.w);
            o1.x = f2bf(x1.x); o1.y = f2bf(x1.y); o1.z = f2bf(x1.z); o1.w = f2bf(x1.w);
            *(ushort4*)(xcp + (size_t)c0 * NHW + n4) = o0;
            *(ushort4*)(xcp + (size_t)c1 * NHW + n4) = o1;
            float w0 = value_w[c0], w1 = value_w[c1];
            vacc.x += x0.x * w0 + x1.x * w1; vacc.y += x0.y * w0 + x1.y * w1;
            vacc.z += x0.z * w0 + x1.z * w1; vacc.w += x0.w * w0 + x1.w * w1;
        }
        // compute: 2 k-chunks of 32 from current slab
        const int cur = cc & 1;
        #pragma unroll
        for (int kc = 0; kc < 2; ++kc) {
            short8 af;
            #pragma unroll
            for (int j = 0; j < 8; ++j)
                af[j] = (short)f2bf(Xs[cur][kc * 32 + quad * 8 + j][nw * 16 + l15]);
            const int g = cc * 2 + kc;       // global k-chunk 0..7
            #pragma unroll
            for (int ct = 0; ct < 8; ++ct) {
                int co = ch * 128 + ct * 16 + l15;
                const float* kr = key_w + (size_t)co * NC + g * 32 + quad * 8;
                const float* qr = query_w + (size_t)co * NC + g * 32 + quad * 8;
                short8 bk = ldw_bf16(kr);
                short8 bq = ldw_bf16(qr);
                accK[ct] = __builtin_amdgcn_mfma_f32_16x16x32_bf16(af, bk, accK[ct], 0, 0, 0);
                accQ[ct] = __builtin_amdgcn_mfma_f32_16x16x32_bf16(af, bq, accQ[ct], 0, 0, 0);
            }
        }
        if (cc < 3) {
            const int nxt = (cc + 1) & 1;
            float* r0 = &Xs[nxt][c_l][n4];
            r0[0] = x0.x; r0[1] = x0.y; r0[2] = x0.z; r0[3] = x0.w;
            float* r1 = &Xs[nxt][c_l + 32][n4];
            r1[0] = x1.x; r1[1] = x1.y; r1[2] = x1.z; r1[3] = x1.w;
            __syncthreads();
        }
    }

    // v: reduce across quads within the wave (lanes with same l15 hold
    // different channels), then across waves via LDS.
    vacc.x += __shfl_xor(vacc.x, 16, 64); vacc.x += __shfl_xor(vacc.x, 32, 64);
    vacc.y += __shfl_xor(vacc.y, 16, 64); vacc.y += __shfl_xor(vacc.y, 32, 64);
    vacc.z += __shfl_xor(vacc.z, 16, 64); vacc.z += __shfl_xor(vacc.z, 32, 64);
    vacc.w += __shfl_xor(vacc.w, 16, 64); vacc.w += __shfl_xor(vacc.w, 32, 64);

    // row-norm partials: rows n = n0 + nw*16 + quad*4 + r, cols = wave's 128 co
    float nK[4] = {0, 0, 0, 0}, nQ[4] = {0, 0, 0, 0};
    #pragma unroll
    for (int ct = 0; ct < 8; ++ct)
        #pragma unroll
        for (int r = 0; r < 4; ++r) {
            nK[r] += accK[ct][r] * accK[ct][r];
            nQ[r] += accQ[ct][r] * accQ[ct][r];
        }
    #pragma unroll
    for (int r = 0; r < 4; ++r)
        #pragma unroll
        for (int o = 1; o < 16; o <<= 1) {
            nK[r] += __shfl_xor(nK[r], o, 64);
            nQ[r] += __shfl_xor(nQ[r], o, 64);
        }
    if (l15 == 0)
        #pragma unroll
        for (int r = 0; r < 4; ++r) {
            PK[ch][nw][quad * 4 + r] = nK[r];
            PQ[ch][nw][quad * 4 + r] = nQ[r];
        }
    if (lane < 16) vred[wave][l15] = vacc;
    __syncthreads();

    float ik[4], iq[4];
    #pragma unroll
    for (int r = 0; r < 4; ++r) {
        float sk = PK[0][nw][quad * 4 + r] + PK[1][nw][quad * 4 + r];
        float sq = PQ[0][nw][quad * 4 + r] + PQ[1][nw][quad * 4 + r];
        ik[r] = 1.f / fmaxf(sqrtf(sk), 1e-12f);
        iq[r] = 1.f / fmaxf(sqrtf(sq), 1e-12f);
    }
    #pragma unroll
    for (int ct = 0; ct < 8; ++ct)
        #pragma unroll
        for (int r = 0; r < 4; ++r) {
            size_t row = (size_t)(b * NHW + n0 + nw * 16 + quad * 4 + r) * NC
                       + ch * 128 + ct * 16 + l15;
            Kn[row] = f2bf(accK[ct][r] * ik[r]);
            Qn[row] = f2bf(accQ[ct][r] * iq[r]);
        }
    if (t < 16) {
        float4 s = {0.f, 0.f, 0.f, 0.f};
        #pragma unroll
        for (int w = 0; w < 8; ++w) {
            float4 p = vred[w][t];
            s.x += p.x; s.y += p.y; s.z += p.z; s.w += p.w;
        }
        float vb = value_b[0];
        s.x += vb; s.y += vb; s.z += vb; s.w += vb;
        *(float4*)(vout + b * NHW + n0 + t * 4) = s;
    }
}

// Per (b, 64 m-cols): 8 waves each own an n-eighth; per-iter 32 MFMAs in
// 8 independent depth-4 chains. Halves Kn L2 redundancy vs m-tile 32.
__global__ __launch_bounds__(512) void attn_kernel(
    const unsigned short* __restrict__ Kn,
    const unsigned short* __restrict__ Qn,
    const float* __restrict__ vbuf,
    float* __restrict__ R)
{
    const int b = blockIdx.y, m0 = blockIdx.x * 64;
    const int t = threadIdx.x, wave = t >> 6, lane = t & 63;
    const int l15 = lane & 15, quad = lane >> 4;

    short8 bf[4][8];
    #pragma unroll
    for (int ms = 0; ms < 4; ++ms) {
        const short* q = (const short*)Qn
                       + (size_t)(b * NHW + m0 + ms * 16 + l15) * NC + quad * 8;
        #pragma unroll
        for (int c = 0; c < 8; ++c) bf[ms][c] = *(const short8*)(q + 32 * c);
    }
    const float* vb = vbuf + b * NHW;
    const int nstart = wave * 128;
    const short* ka = (const short*)Kn + (size_t)(b * NHW + nstart + l15) * NC + quad * 8;

    float z[4] = {0.f, 0.f, 0.f, 0.f}, tc[4] = {0.f, 0.f, 0.f, 0.f};
    for (int it = 0; it < 8; ++it, ka += 16 * NC) {
        short8 af[8];
        #pragma unroll
        for (int c = 0; c < 8; ++c) af[c] = *(const short8*)(ka + 32 * c);
        f32x4 a0[4], a1[4];
        #pragma unroll
        for (int ms = 0; ms < 4; ++ms) { a0[ms] = (f32x4){0,0,0,0}; a1[ms] = (f32x4){0,0,0,0}; }
        #pragma unroll
        for (int c = 0; c < 4; ++c)
            #pragma unroll
            for (int ms = 0; ms < 4; ++ms) {
                a0[ms] = __builtin_amdgcn_mfma_f32_16x16x32_bf16(af[c],     bf[ms][c],     a0[ms], 0, 0, 0);
                a1[ms] = __builtin_amdgcn_mfma_f32_16x16x32_bf16(af[c + 4], bf[ms][c + 4], a1[ms], 0, 0, 0);
            }
        float4 vv = *(const float4*)(vb + nstart + it * 16 + quad * 4);
        #pragma unroll
        for (int ms = 0; ms < 4; ++ms)
            #pragma unroll
            for (int r = 0; r < 4; ++r) {
                float e = __expf(a0[ms][r] + a1[ms][r]);
                z[ms] += e;
                tc[ms] += ((const float*)&vv)[r] * e;
            }
    }
    #pragma unroll
    for (int ms = 0; ms < 4; ++ms) {
        z[ms]  += __shfl_xor(z[ms], 16, 64);  z[ms]  += __shfl_xor(z[ms], 32, 64);
        tc[ms] += __shfl_xor(tc[ms], 16, 64); tc[ms] += __shfl_xor(tc[ms], 32, 64);
    }

    __shared__ float zs[8][4][16], ts[8][4][16];
    if (lane < 16)
        #pragma unroll
        for (int ms = 0; ms < 4; ++ms) {
            zs[wave][ms][l15] = z[ms];
            ts[wave][ms][l15] = tc[ms];
        }
    __syncthreads();
    if (t < 64) {
        int ms = t >> 4, li = t & 15;
        float zz = 0.f, tt = 0.f;
        #pragma unroll
        for (int w = 0; w < 8; ++w) { zz += zs[w][ms][li]; tt += ts[w][ms][li]; }
        R[b * NHW + m0 + ms * 16 + li] = tt / zz;
    }
}

// out[b,c,i,j] = 3x3 box sum over P[m] = R[b,m]*xc[b,c,m]  (xc bf16)
__global__ __launch_bounds__(256) void out_kernel(
    const unsigned short* __restrict__ xc,
    const float* __restrict__ R,
    float* __restrict__ out)
{
    const int bc = blockIdx.x;
    const int b  = bc >> 8;
    const int t  = threadIdx.x;
    __shared__ float P[NHW];

    const unsigned short* xp = xc + (size_t)bc * NHW;
    const float* rp = R + b * NHW;
    {
        ushort4 xv = *(const ushort4*)(xp + t * 4);
        float4  rv = *(const float4*)(rp + t * 4);
        P[t * 4 + 0] = rv.x * bf2f(xv.x);
        P[t * 4 + 1] = rv.y * bf2f(xv.y);
        P[t * 4 + 2] = rv.z * bf2f(xv.z);
        P[t * 4 + 3] = rv.w * bf2f(xv.w);
    }
    __syncthreads();
    for (int idx = t; idx < NCH * NCH; idx += 256) {
        int i = idx / NCH, j = idx - i * NCH;
        const float* pr = &P[i * 32 + j];
        float s = pr[0]  + pr[1]  + pr[2]
                + pr[32] + pr[33] + pr[34]
                + pr[64] + pr[65] + pr[66];
        out[(size_t)bc * (NCH * NCH) + idx] = s;
    }
}

extern "C" void kernel_launch(void* const* d_in, const int* in_sizes, int n_in,
                              void* d_out, int out_size, void* d_ws, size_t ws_size,
                              hipStream_t stream) {
    const float* batch   = (const float*)d_in[0];
    const float* key_w   = (const float*)d_in[1];
    const float* key_b   = (const float*)d_in[2];
    const float* query_w = (const float*)d_in[3];
    const float* query_b = (const float*)d_in[4];
    const float* value_w = (const float*)d_in[5];
    const float* value_b = (const float*)d_in[6];
    float* out = (float*)d_out;

    char* ws = (char*)d_ws;
    const size_t KQ = (size_t)NB * NHW * NC;            // 4,194,304 elems
    unsigned short* xc  = (unsigned short*)ws;                        // 8MB
    unsigned short* Kn  = xc + KQ;                                    // 8MB
    unsigned short* Qn  = Kn + KQ;                                    // 8MB
    float* vbuf = (float*)(Qn + KQ);                                  // 64KB
    float* Rbuf = vbuf + NB * NHW;                                    // 64KB

    fused_lin_kernel<<<dim3(16, NB), 512, 0, stream>>>(batch, value_w, value_b,
                                                       key_w, query_w, key_b, query_b,
                                                       xc, Kn, Qn, vbuf);
    attn_kernel<<<dim3(16, NB), 512, 0, stream>>>(Kn, Qn, vbuf, Rbuf);
    out_kernel<<<NB * NC, 256, 0, stream>>>(xc, Rbuf, out);
}

// Round 6
// 146.362 us; speedup vs baseline: 1.1794x; 1.1794x over previous
//
#include <hip/hip_runtime.h>
#include <hip/hip_bf16.h>

// ConvolutionalSelfAttention — algebraically reduced:
//   Kn[b,n,:] = normalize(x[b,n,:] @ key_w^T + key_b)      (bf16, via MFMA)
//   Qn[b,m,:] = normalize(x[b,m,:] @ query_w^T + query_b)  (bf16, via MFMA)
//   v[b,n]    = x[b,n,:] @ value_w^T + value_b             (fp32)
//   S[b,n,m]  = Kn[b,n]·Qn[b,m]   (|S|<=1, exp stable without max-sub)
//   R[b,m]    = (sum_n v e^S) / (sum_n e^S)                (fused, S never stored)
//   out[b,c,i,j] = 3x3 box sum of R[b,m]*x[b,c,m]  (x in bf16 copy xc)
// local_indices unused (windows are complete 3x3, order-invariant).
// R5->R6: inline weight conversion REVERTED (it serialized L2 loads on 80
//         VGPRs -> ~43us of exposed latency). wconv kernel is back; weight
//         fragments now double-buffered in registers (ping-pong prefetch of
//         k-chunk g+1 while MFMAing g), launch_bounds(512,2) for ~256 VGPRs.
// ws: xc 8MB | Kn 8MB | Qn 8MB | kwb 128KB | qwb 128KB | v 64KB | R 64KB

#define NB 16
#define NC 256
#define NHW 1024
#define NCH 30

typedef __attribute__((ext_vector_type(8))) short short8;
typedef __attribute__((ext_vector_type(4))) float f32x4;

static __device__ __forceinline__ unsigned short f2bf(float f) {
    __hip_bfloat16 h = __float2bfloat16(f);
    return *(unsigned short*)&h;
}
static __device__ __forceinline__ float bf2f(unsigned short u) {
    unsigned int x = ((unsigned int)u) << 16;
    return __uint_as_float(x);
}

// fp32 -> bf16 weight conversion (32 blocks: 16 per matrix)
__global__ __launch_bounds__(256) void wconv_kernel(
    const float* __restrict__ key_w, const float* __restrict__ query_w,
    unsigned short* __restrict__ kwb, unsigned short* __restrict__ qwb)
{
    const int gx = blockIdx.x, t = threadIdx.x;
    const float* src = (gx < 16) ? key_w : query_w;
    unsigned short* dst = (gx < 16) ? kwb : qwb;
    int base = (gx & 15) * 4096;
    #pragma unroll
    for (int k = 0; k < 4; ++k) {
        int i = base + (k * 256 + t) * 4;
        float4 a = *(const float4*)(src + i);
        ushort4 o;
        o.x = f2bf(a.x); o.y = f2bf(a.y); o.z = f2bf(a.z); o.w = f2bf(a.w);
        *(ushort4*)(dst + i) = o;
    }
}

// Fused: transpose batch -> (LDS fp32 slab, xc bf16 copy) + v + MFMA linears
// + row-normalize -> Kn, Qn.  Grid (16 n-tiles, B), 512 threads (8 waves:
// nw = wave&3 picks 16-row n-subtile, ch = wave>>2 picks 128-col co-half).
// Weight B-fragments are ping-pong prefetched one k-chunk ahead.
__global__ __launch_bounds__(512, 2) void fused_lin_kernel(
    const float* __restrict__ batch,
    const float* __restrict__ value_w, const float* __restrict__ value_b,
    const unsigned short* __restrict__ kwb, const unsigned short* __restrict__ qwb,
    const float* __restrict__ key_b, const float* __restrict__ query_b,
    unsigned short* __restrict__ xc,
    unsigned short* __restrict__ Kn, unsigned short* __restrict__ Qn,
    float* __restrict__ vout)
{
    const int b = blockIdx.y, n0 = blockIdx.x * 64;
    const int t = threadIdx.x, wave = t >> 6, lane = t & 63;
    const int nw = wave & 3, ch = wave >> 2;
    const int l15 = lane & 15, quad = lane >> 4;

    __shared__ float Xs[2][64][65];          // [buf][k-in-slab][n], stride 65
    __shared__ float PK[2][4][16], PQ[2][4][16];
    __shared__ float4 vred[8][16];

    // staging roles: thread loads rows c_l and c_l+32 of the 64-c slab, 4 n's
    const int c_l = t >> 4;                  // 0..31  (= wave*4 + quad)
    const int n4  = (t & 15) * 4;
    const float* bb = batch + (size_t)b * NC * NHW + n0;
    unsigned short* xcp = xc + (size_t)b * NC * NHW + n0;
    float4 vacc = {0.f, 0.f, 0.f, 0.f};

    // weight fragment base: row co = ch*128 + ct*16 + l15, k offset quad*8
    const short* kbase = (const short*)kwb + (size_t)(ch * 128 + l15) * NC + quad * 8;
    const short* qbase = (const short*)qwb + (size_t)(ch * 128 + l15) * NC + quad * 8;

    short8 wK[2][8], wQ[2][8];
    #pragma unroll
    for (int ct = 0; ct < 8; ++ct) {        // prefetch k-chunk 0
        wK[0][ct] = *(const short8*)(kbase + ct * 16 * NC);
        wQ[0][ct] = *(const short8*)(qbase + ct * 16 * NC);
    }

    float4 x0, x1;
    // prologue: load slab 0
    {
        int c0 = c_l, c1 = c_l + 32;
        x0 = *(const float4*)(bb + (size_t)c0 * NHW + n4);
        x1 = *(const float4*)(bb + (size_t)c1 * NHW + n4);
        ushort4 o0, o1;
        o0.x = f2bf(x0.x); o0.y = f2bf(x0.y); o0.z = f2bf(x0.z); o0.w = f2bf(x0.w);
        o1.x = f2bf(x1.x); o1.y = f2bf(x1.y); o1.z = f2bf(x1.z); o1.w = f2bf(x1.w);
        *(ushort4*)(xcp + (size_t)c0 * NHW + n4) = o0;
        *(ushort4*)(xcp + (size_t)c1 * NHW + n4) = o1;
        float w0 = value_w[c0], w1 = value_w[c1];
        vacc.x += x0.x * w0 + x1.x * w1; vacc.y += x0.y * w0 + x1.y * w1;
        vacc.z += x0.z * w0 + x1.z * w1; vacc.w += x0.w * w0 + x1.w * w1;
        float* r0 = &Xs[0][c_l][n4];
        r0[0] = x0.x; r0[1] = x0.y; r0[2] = x0.z; r0[3] = x0.w;
        float* r1 = &Xs[0][c_l + 32][n4];
        r1[0] = x1.x; r1[1] = x1.y; r1[2] = x1.z; r1[3] = x1.w;
    }
    __syncthreads();

    f32x4 accK[8], accQ[8];
    #pragma unroll
    for (int ct = 0; ct < 8; ++ct) {
        int co = ch * 128 + ct * 16 + l15;
        float bK = key_b[co], bQ = query_b[co];
        accK[ct] = (f32x4){bK, bK, bK, bK};
        accQ[ct] = (f32x4){bQ, bQ, bQ, bQ};
    }

    for (int cc = 0; cc < 4; ++cc) {
        // prefetch next slab into registers (latency hidden by MFMA below)
        if (cc < 3) {
            int c0 = (cc + 1) * 64 + c_l, c1 = c0 + 32;
            x0 = *(const float4*)(bb + (size_t)c0 * NHW + n4);
            x1 = *(const float4*)(bb + (size_t)c1 * NHW + n4);
            ushort4 o0, o1;
            o0.x = f2bf(x0.x); o0.y = f2bf(x0.y); o0.z = f2bf(x0.z); o0.w = f2bf(x0.w);
            o1.x = f2bf(x1.x); o1.y = f2bf(x1.y); o1.z = f2bf(x1.z); o1.w = f2bf(x1.w);
            *(ushort4*)(xcp + (size_t)c0 * NHW + n4) = o0;
            *(ushort4*)(xcp + (size_t)c1 * NHW + n4) = o1;
            float w0 = value_w[c0], w1 = value_w[c1];
            vacc.x += x0.x * w0 + x1.x * w1; vacc.y += x0.y * w0 + x1.y * w1;
            vacc.z += x0.z * w0 + x1.z * w1; vacc.w += x0.w * w0 + x1.w * w1;
        }
        // compute: 2 k-chunks of 32 from current slab
        const int cur = cc & 1;
        #pragma unroll
        for (int kc = 0; kc < 2; ++kc) {
            const int g = cc * 2 + kc;       // global k-chunk 0..7
            // issue next k-chunk's weight loads before consuming current
            if (g < 7) {
                const int nb_ = (g + 1) & 1;
                #pragma unroll
                for (int ct = 0; ct < 8; ++ct) {
                    wK[nb_][ct] = *(const short8*)(kbase + ct * 16 * NC + (g + 1) * 32);
                    wQ[nb_][ct] = *(const short8*)(qbase + ct * 16 * NC + (g + 1) * 32);
                }
            }
            short8 af;
            #pragma unroll
            for (int j = 0; j < 8; ++j)
                af[j] = (short)f2bf(Xs[cur][kc * 32 + quad * 8 + j][nw * 16 + l15]);
            const int cb = g & 1;
            #pragma unroll
            for (int ct = 0; ct < 8; ++ct) {
                accK[ct] = __builtin_amdgcn_mfma_f32_16x16x32_bf16(af, wK[cb][ct], accK[ct], 0, 0, 0);
                accQ[ct] = __builtin_amdgcn_mfma_f32_16x16x32_bf16(af, wQ[cb][ct], accQ[ct], 0, 0, 0);
            }
        }
        if (cc < 3) {
            const int nxt = (cc + 1) & 1;
            float* r0 = &Xs[nxt][c_l][n4];
            r0[0] = x0.x; r0[1] = x0.y; r0[2] = x0.z; r0[3] = x0.w;
            float* r1 = &Xs[nxt][c_l + 32][n4];
            r1[0] = x1.x; r1[1] = x1.y; r1[2] = x1.z; r1[3] = x1.w;
            __syncthreads();
        }
    }

    // v: reduce across quads within the wave, then across waves via LDS.
    vacc.x += __shfl_xor(vacc.x, 16, 64); vacc.x += __shfl_xor(vacc.x, 32, 64);
    vacc.y += __shfl_xor(vacc.y, 16, 64); vacc.y += __shfl_xor(vacc.y, 32, 64);
    vacc.z += __shfl_xor(vacc.z, 16, 64); vacc.z += __shfl_xor(vacc.z, 32, 64);
    vacc.w += __shfl_xor(vacc.w, 16, 64); vacc.w += __shfl_xor(vacc.w, 32, 64);

    // row-norm partials: rows n = n0 + nw*16 + quad*4 + r, cols = wave's 128 co
    float nK[4] = {0, 0, 0, 0}, nQ[4] = {0, 0, 0, 0};
    #pragma unroll
    for (int ct = 0; ct < 8; ++ct)
        #pragma unroll
        for (int r = 0; r < 4; ++r) {
            nK[r] += accK[ct][r] * accK[ct][r];
            nQ[r] += accQ[ct][r] * accQ[ct][r];
        }
    #pragma unroll
    for (int r = 0; r < 4; ++r)
        #pragma unroll
        for (int o = 1; o < 16; o <<= 1) {
            nK[r] += __shfl_xor(nK[r], o, 64);
            nQ[r] += __shfl_xor(nQ[r], o, 64);
        }
    if (l15 == 0)
        #pragma unroll
        for (int r = 0; r < 4; ++r) {
            PK[ch][nw][quad * 4 + r] = nK[r];
            PQ[ch][nw][quad * 4 + r] = nQ[r];
        }
    if (lane < 16) vred[wave][l15] = vacc;
    __syncthreads();

    float ik[4], iq[4];
    #pragma unroll
    for (int r = 0; r < 4; ++r) {
        float sk = PK[0][nw][quad * 4 + r] + PK[1][nw][quad * 4 + r];
        float sq = PQ[0][nw][quad * 4 + r] + PQ[1][nw][quad * 4 + r];
        ik[r] = 1.f / fmaxf(sqrtf(sk), 1e-12f);
        iq[r] = 1.f / fmaxf(sqrtf(sq), 1e-12f);
    }
    #pragma unroll
    for (int ct = 0; ct < 8; ++ct)
        #pragma unroll
        for (int r = 0; r < 4; ++r) {
            size_t row = (size_t)(b * NHW + n0 + nw * 16 + quad * 4 + r) * NC
                       + ch * 128 + ct * 16 + l15;
            Kn[row] = f2bf(accK[ct][r] * ik[r]);
            Qn[row] = f2bf(accQ[ct][r] * iq[r]);
        }
    if (t < 16) {
        float4 s = {0.f, 0.f, 0.f, 0.f};
        #pragma unroll
        for (int w = 0; w < 8; ++w) {
            float4 p = vred[w][t];
            s.x += p.x; s.y += p.y; s.z += p.z; s.w += p.w;
        }
        float vb = value_b[0];
        s.x += vb; s.y += vb; s.z += vb; s.w += vb;
        *(float4*)(vout + b * NHW + n0 + t * 4) = s;
    }
}

// Per (b, 64 m-cols): 8 waves each own an n-eighth; per-iter 32 MFMAs in
// 8 independent depth-4 chains. Halves Kn L2 redundancy vs m-tile 32.
__global__ __launch_bounds__(512) void attn_kernel(
    const unsigned short* __restrict__ Kn,
    const unsigned short* __restrict__ Qn,
    const float* __restrict__ vbuf,
    float* __restrict__ R)
{
    const int b = blockIdx.y, m0 = blockIdx.x * 64;
    const int t = threadIdx.x, wave = t >> 6, lane = t & 63;
    const int l15 = lane & 15, quad = lane >> 4;

    short8 bf[4][8];
    #pragma unroll
    for (int ms = 0; ms < 4; ++ms) {
        const short* q = (const short*)Qn
                       + (size_t)(b * NHW + m0 + ms * 16 + l15) * NC + quad * 8;
        #pragma unroll
        for (int c = 0; c < 8; ++c) bf[ms][c] = *(const short8*)(q + 32 * c);
    }
    const float* vb = vbuf + b * NHW;
    const int nstart = wave * 128;
    const short* ka = (const short*)Kn + (size_t)(b * NHW + nstart + l15) * NC + quad * 8;

    float z[4] = {0.f, 0.f, 0.f, 0.f}, tc[4] = {0.f, 0.f, 0.f, 0.f};
    for (int it = 0; it < 8; ++it, ka += 16 * NC) {
        short8 af[8];
        #pragma unroll
        for (int c = 0; c < 8; ++c) af[c] = *(const short8*)(ka + 32 * c);
        f32x4 a0[4], a1[4];
        #pragma unroll
        for (int ms = 0; ms < 4; ++ms) { a0[ms] = (f32x4){0,0,0,0}; a1[ms] = (f32x4){0,0,0,0}; }
        #pragma unroll
        for (int c = 0; c < 4; ++c)
            #pragma unroll
            for (int ms = 0; ms < 4; ++ms) {
                a0[ms] = __builtin_amdgcn_mfma_f32_16x16x32_bf16(af[c],     bf[ms][c],     a0[ms], 0, 0, 0);
                a1[ms] = __builtin_amdgcn_mfma_f32_16x16x32_bf16(af[c + 4], bf[ms][c + 4], a1[ms], 0, 0, 0);
            }
        float4 vv = *(const float4*)(vb + nstart + it * 16 + quad * 4);
        #pragma unroll
        for (int ms = 0; ms < 4; ++ms)
            #pragma unroll
            for (int r = 0; r < 4; ++r) {
                float e = __expf(a0[ms][r] + a1[ms][r]);
                z[ms] += e;
                tc[ms] += ((const float*)&vv)[r] * e;
            }
    }
    #pragma unroll
    for (int ms = 0; ms < 4; ++ms) {
        z[ms]  += __shfl_xor(z[ms], 16, 64);  z[ms]  += __shfl_xor(z[ms], 32, 64);
        tc[ms] += __shfl_xor(tc[ms], 16, 64); tc[ms] += __shfl_xor(tc[ms], 32, 64);
    }

    __shared__ float zs[8][4][16], ts[8][4][16];
    if (lane < 16)
        #pragma unroll
        for (int ms = 0; ms < 4; ++ms) {
            zs[wave][ms][l15] = z[ms];
            ts[wave][ms][l15] = tc[ms];
        }
    __syncthreads();
    if (t < 64) {
        int ms = t >> 4, li = t & 15;
        float zz = 0.f, tt = 0.f;
        #pragma unroll
        for (int w = 0; w < 8; ++w) { zz += zs[w][ms][li]; tt += ts[w][ms][li]; }
        R[b * NHW + m0 + ms * 16 + li] = tt / zz;
    }
}

// out[b,c,i,j] = 3x3 box sum over P[m] = R[b,m]*xc[b,c,m]  (xc bf16)
__global__ __launch_bounds__(256) void out_kernel(
    const unsigned short* __restrict__ xc,
    const float* __restrict__ R,
    float* __restrict__ out)
{
    const int bc = blockIdx.x;
    const int b  = bc >> 8;
    const int t  = threadIdx.x;
    __shared__ float P[NHW];

    const unsigned short* xp = xc + (size_t)bc * NHW;
    const float* rp = R + b * NHW;
    {
        ushort4 xv = *(const ushort4*)(xp + t * 4);
        float4  rv = *(const float4*)(rp + t * 4);
        P[t * 4 + 0] = rv.x * bf2f(xv.x);
        P[t * 4 + 1] = rv.y * bf2f(xv.y);
        P[t * 4 + 2] = rv.z * bf2f(xv.z);
        P[t * 4 + 3] = rv.w * bf2f(xv.w);
    }
    __syncthreads();
    for (int idx = t; idx < NCH * NCH; idx += 256) {
        int i = idx / NCH, j = idx - i * NCH;
        const float* pr = &P[i * 32 + j];
        float s = pr[0]  + pr[1]  + pr[2]
                + pr[32] + pr[33] + pr[34]
                + pr[64] + pr[65] + pr[66];
        out[(size_t)bc * (NCH * NCH) + idx] = s;
    }
}

extern "C" void kernel_launch(void* const* d_in, const int* in_sizes, int n_in,
                              void* d_out, int out_size, void* d_ws, size_t ws_size,
                              hipStream_t stream) {
    const float* batch   = (const float*)d_in[0];
    const float* key_w   = (const float*)d_in[1];
    const float* key_b   = (const float*)d_in[2];
    const float* query_w = (const float*)d_in[3];
    const float* query_b = (const float*)d_in[4];
    const float* value_w = (const float*)d_in[5];
    const float* value_b = (const float*)d_in[6];
    float* out = (float*)d_out;

    char* ws = (char*)d_ws;
    const size_t KQ = (size_t)NB * NHW * NC;            // 4,194,304 elems
    unsigned short* xc  = (unsigned short*)ws;                        // 8MB
    unsigned short* Kn  = xc + KQ;                                    // 8MB
    unsigned short* Qn  = Kn + KQ;                                    // 8MB
    unsigned short* kwb = Qn + KQ;                                    // 128KB
    unsigned short* qwb = kwb + NC * NC;                              // 128KB
    float* vbuf = (float*)(qwb + NC * NC);                            // 64KB
    float* Rbuf = vbuf + NB * NHW;                                    // 64KB

    wconv_kernel<<<32, 256, 0, stream>>>(key_w, query_w, kwb, qwb);
    fused_lin_kernel<<<dim3(16, NB), 512, 0, stream>>>(batch, value_w, value_b,
                                                       kwb, qwb, key_b, query_b,
                                                       xc, Kn, Qn, vbuf);
    attn_kernel<<<dim3(16, NB), 512, 0, stream>>>(Kn, Qn, vbuf, Rbuf);
    out_kernel<<<NB * NC, 256, 0, stream>>>(xc, Rbuf, out);
}